// Round 8
// baseline (136.997 us; speedup 1.0000x reference)
//
#include <hip/hip_runtime.h>
#include <hip/hip_bf16.h>
#include <cstdio>

typedef __hip_bfloat16 bf16;
typedef __bf16 bf16x8 __attribute__((ext_vector_type(8)));
typedef float f32x4 __attribute__((ext_vector_type(4)));

#define B_DIM 4
#define T_DIM 4096
#define D_DIM 1024
#define NC 64   // chunks along T
#define LC 64   // chunk length; NC*LC == T_DIM

#define M_DIM (B_DIM * T_DIM)  // 16384
#define BM 128
#define BN 256
#define BK 32
#define NT (D_DIM / BK)        // 32 K-tiles
#define GM (M_DIM / BM)        // 128
#define GN (D_DIM / BN)        // 4

// ---------------------------------------------------------------- weight cast
__global__ __launch_bounds__(256) void cast_w_kernel(
    const float* __restrict__ gw, const float* __restrict__ ow,
    bf16* __restrict__ gw16, bf16* __restrict__ ow16, int n) {
  int i = blockIdx.x * 256 + threadIdx.x;
  if (i < n) {
    gw16[i] = __float2bfloat16(gw[i]);
    ow16[i] = __float2bfloat16(ow[i]);
  }
}

// ---------------------------------------------------------------- SSM pass 1
__global__ __launch_bounds__(256) void ssm_pass1(
    const float* __restrict__ x, const float* __restrict__ A,
    const float* __restrict__ Bp, float* __restrict__ hfin) {
  const int tid  = threadIdx.x;
  const int dblk = blockIdx.x & 3;           // D/256 = 4
  const int c    = (blockIdx.x >> 2) & (NC - 1);
  const int b    = blockIdx.x >> 8;          // / (4*NC)
  const int d    = dblk * 256 + tid;
  const float a = A[d], bp = Bp[d];
  const float* p = x + ((size_t)(b * T_DIM + c * LC) * D_DIM + d);
  float h = 0.f;
#pragma unroll 4
  for (int i = 0; i < LC; ++i)
    h = fmaf(a, h, bp * p[(size_t)i * D_DIM]);
  hfin[(b * NC + c) * D_DIM + d] = h;
}

// ---------------------------------------------------------------- SSM pass 2
__global__ __launch_bounds__(256) void ssm_pass2(
    const float* __restrict__ A, const float* __restrict__ hfin,
    float* __restrict__ hin) {
  const int idx = blockIdx.x * 256 + threadIdx.x;  // B*D = 4096
  const int d = idx & (D_DIM - 1);
  const int b = idx >> 10;
  float aL = A[d];
#pragma unroll
  for (int s = 0; s < 6; ++s) aL *= aL;  // A^64 (LC = 2^6)
  float h = 0.f;
  for (int c = 0; c < NC; ++c) {
    const int o = (b * NC + c) * D_DIM + d;
    hin[o] = h;
    h = fmaf(aL, h, hfin[o]);
  }
}

// ---------------------------------------------------------------- SSM pass 3
__global__ __launch_bounds__(256) void ssm_pass3(
    const float* __restrict__ x, const float* __restrict__ A,
    const float* __restrict__ Bp, const float* __restrict__ Cp,
    const float* __restrict__ hin, bf16* __restrict__ ssm16,
    bf16* __restrict__ x16) {
  const int tid  = threadIdx.x;
  const int dblk = blockIdx.x & 3;
  const int c    = (blockIdx.x >> 2) & (NC - 1);
  const int b    = blockIdx.x >> 8;
  const int d    = dblk * 256 + tid;
  const float a = A[d], bp = Bp[d], cp = Cp[d];
  float h = hin[(b * NC + c) * D_DIM + d];
  const size_t base = (size_t)(b * T_DIM + c * LC) * D_DIM + d;
#pragma unroll 4
  for (int i = 0; i < LC; ++i) {
    const size_t o = base + (size_t)i * D_DIM;
    const float xv = x[o];
    h = fmaf(a, h, bp * xv);
    ssm16[o] = __float2bfloat16(cp * h);
    x16[o]  = __float2bfloat16(xv);
  }
}

// ---------------------------------------------------------------- GEMM 128x256
// C[m][e] = sum_k X[m][k] * W[e][k]  (+bias, +epilogue)
// R8: tile 128x256, 4 waves (1M x 4N), per-wave C = 128x64 (8x4 frags,
// IDENTICAL inner loop to R7). Ring-3 LDS (3 x 24 KiB = 72 KiB) ->
// 2 blocks/CU: two independent barrier domains per CU so one block's
// MFMAs cover the other's vmcnt/barrier drain (m114 cross-block overlap).
// Prefetch distance 2; counted vmcnt ledger:
//   prologue: STAGE(t0)+STAGE(t1) = 12 loads; vmcnt(6) [t0 done]; barrier.
//   tile t (0..NT-3): reads buf[t%3]; STAGE((t+2)%3, t+2); lgkmcnt(0);
//     MFMA half1; vmcnt(6) [<=6 left = t+2's stage => t+1 landed]; barrier;
//     MFMA half2 (reg-only, overlaps next tile's reads).
//   tile NT-2: no stage; vmcnt(0) [t=NT-1 landed]; tile NT-1: no barrier.
// Buffer lifetime: STAGE(t+2) overwrites buf[(t+2)%3] == buf[(t-1)%3];
// all reads of buf[t-1] completed before tile t-1's lgkmcnt(0), which
// precedes tile t-1's mid-barrier, which every wave passed before any
// wave issues STAGE(t+2) at tile t. T2 XOR swizzle both-sides (conflicts
// measured 0), T5 setprio, XCD-chunked block swizzle retained from R7.
template <bool GATE>
__global__ __launch_bounds__(256, 2) void gemm128(
    const bf16* __restrict__ Xm, const bf16* __restrict__ Wm,
    const float* __restrict__ bias, const bf16* __restrict__ ssm,
    bf16* __restrict__ Ybf, float* __restrict__ Yf) {
  // buf layout (shorts): [0,4096) = A tile 128x32, [4096,12288) = B tile 256x32
  __shared__ __align__(16) short LDS[3][12288];  // 3 x 24 KiB = 72 KiB

  const int tid  = threadIdx.x;
  const int lane = tid & 63;
  const int wave = tid >> 6;          // 0..3 = N-quadrant
  const int l15 = lane & 15;
  // swizzled ds_read slot: true chunk (lane>>4), row parity term (l15>>1)&3
  const int sA = ((lane >> 4) ^ ((l15 >> 1) & 3)) << 3;  // shorts

  // XCD-chunked swizzle (512 blocks, 8 XCDs, 64/XCD): the 4 N-blocks of
  // each M-row are consecutive within an XCD chunk (A-panel L2 reuse).
  const int bid = blockIdx.x;
  const int swz = (bid & 7) * (GM * GN / 8) + (bid >> 3);
  const int m0 = (swz >> 2) * BM;
  const int n0 = (swz & 3) * BN;

  // staging: row = 4 chunks of 16B (32 shorts). linear LDS chunk cid ->
  // row=cid>>2, slot=cid&3; global col-chunk c = slot ^ ((row>>1)&3)
  // (involution matches sA on the read side).
  const int row0 = tid >> 2;          // 0..63
  const int c0   = (tid & 3) ^ ((row0 >> 1) & 3);
  size_t offA[2], offB[4];
#pragma unroll
  for (int it = 0; it < 2; ++it)
    offA[it] = (size_t)(m0 + it * 64 + row0) * D_DIM + c0 * 8;
#pragma unroll
  for (int it = 0; it < 4; ++it)
    offB[it] = (size_t)(n0 + it * 64 + row0) * D_DIM + c0 * 8;

  auto gll = [](const bf16* g, short* l) {
    __builtin_amdgcn_global_load_lds(
        (const __attribute__((address_space(1))) void*)g,
        (__attribute__((address_space(3))) void*)l, 16, 0, 0);
  };
  auto STAGE = [&](int buf, int kt) {
    const size_t ko = (size_t)kt * BK;
#pragma unroll
    for (int it = 0; it < 2; ++it)
      gll(Xm + offA[it] + ko, &LDS[buf][(it * 256 + wave * 64) * 8]);
#pragma unroll
    for (int it = 0; it < 4; ++it)
      gll(Wm + offB[it] + ko, &LDS[buf][4096 + (it * 256 + wave * 64) * 8]);
  };

  f32x4 acc[8][4] = {};

  // prologue: prime tiles 0,1 (12 loads/thread in flight)
  STAGE(0, 0);
  STAGE(1, 1);
  asm volatile("s_waitcnt vmcnt(6)" ::: "memory");
  __builtin_amdgcn_s_barrier();  // tile 0 staged for all waves

#define KTILE_BODY(RB_, SB_, KT2_, VMSTR, DO_STAGE, DO_BAR)                 \
  {                                                                         \
    const short* bb = &LDS[RB_][0];                                         \
    bf16x8 a[8], b[4];                                                      \
    _Pragma("unroll")                                                       \
    for (int i = 0; i < 8; ++i)                                             \
      a[i] = *(const bf16x8*)(bb + (i * 16 + l15) * BK + sA);               \
    _Pragma("unroll")                                                       \
    for (int j = 0; j < 4; ++j)                                             \
      b[j] = *(const bf16x8*)(bb + 4096 + (wave * 64 + j * 16 + l15) * BK + sA); \
    if (DO_STAGE) STAGE(SB_, KT2_);                                         \
    asm volatile("s_waitcnt lgkmcnt(0)" ::: "memory");                      \
    __builtin_amdgcn_sched_barrier(0);                                      \
    __builtin_amdgcn_s_setprio(1);                                          \
    _Pragma("unroll")                                                       \
    for (int i = 0; i < 4; ++i)                                             \
      _Pragma("unroll")                                                     \
      for (int j = 0; j < 4; ++j)                                           \
        acc[i][j] =                                                         \
            __builtin_amdgcn_mfma_f32_16x16x32_bf16(a[i], b[j], acc[i][j], 0, 0, 0); \
    __builtin_amdgcn_s_setprio(0);                                          \
    if (DO_BAR) {                                                           \
      asm volatile("s_waitcnt " VMSTR ::: "memory");                        \
      __builtin_amdgcn_s_barrier();                                         \
    }                                                                       \
    __builtin_amdgcn_s_setprio(1);                                          \
    _Pragma("unroll")                                                       \
    for (int i = 4; i < 8; ++i)                                             \
      _Pragma("unroll")                                                     \
      for (int j = 0; j < 4; ++j)                                           \
        acc[i][j] =                                                         \
            __builtin_amdgcn_mfma_f32_16x16x32_bf16(a[i], b[j], acc[i][j], 0, 0, 0); \
    __builtin_amdgcn_s_setprio(0);                                          \
  }

  {
    int rb = 0;
    for (int t = 0; t < NT - 2; ++t) {  // t = 0..29: stage t+2 = 2..31
      int sb = rb + 2; if (sb >= 3) sb -= 3;
      KTILE_BODY(rb, sb, t + 2, "vmcnt(6)", true, true);
      ++rb; if (rb == 3) rb = 0;
    }
  }
  KTILE_BODY((NT - 2) % 3, 0, 0, "vmcnt(0)", false, true);   // ensure tile 31
  KTILE_BODY((NT - 1) % 3, 0, 0, "vmcnt(0)", false, false);  // last, no barrier
#undef KTILE_BODY

  // ---- epilogue: C/D layout col = lane&15, row = (lane>>4)*4 + v  [m89/m91]
#pragma unroll
  for (int i = 0; i < 8; ++i) {
#pragma unroll
    for (int j = 0; j < 4; ++j) {
      const int col = n0 + wave * 64 + j * 16 + l15;
      const float bv = bias[col];
#pragma unroll
      for (int v = 0; v < 4; ++v) {
        const int row = m0 + i * 16 + (lane >> 4) * 4 + v;
        const size_t o = (size_t)row * D_DIM + col;
        const float val = acc[i][j][v] + bv;
        if (GATE) {
          const float g = 1.f / (1.f + expf(-val));
          Ybf[o] = __float2bfloat16(g * __bfloat162float(ssm[o]));
        } else {
          Yf[o] = val;
        }
      }
    }
  }
}

// ---------------------------------------------------------------- launch
extern "C" void kernel_launch(void* const* d_in, const int* in_sizes, int n_in,
                              void* d_out, int out_size, void* d_ws, size_t ws_size,
                              hipStream_t stream) {
  const float* x  = (const float*)d_in[0];
  const float* A  = (const float*)d_in[1];
  const float* Bp = (const float*)d_in[2];
  const float* Cp = (const float*)d_in[3];
  const float* gw = (const float*)d_in[4];
  const float* gb = (const float*)d_in[5];
  const float* ow = (const float*)d_in[6];
  const float* ob = (const float*)d_in[7];
  float* out = (float*)d_out;

  // workspace layout (bytes)
  const size_t NEED = 73400320;
  if (ws_size < NEED) {
    fprintf(stderr, "kernel_launch: ws_size %zu < needed %zu\n", ws_size, NEED);
    return;
  }
  char* ws = (char*)d_ws;
  bf16*  x16   = (bf16*)(ws);                   // 33,554,432 B : x cast to bf16
  bf16*  ssm16 = (bf16*)(ws + 33554432);        // 33,554,432 B : ssm, then y in-place
  bf16*  gw16  = (bf16*)(ws + 67108864);        //  2,097,152 B
  bf16*  ow16  = (bf16*)(ws + 69206016);        //  2,097,152 B
  float* hfin  = (float*)(ws + 71303168);       //  1,048,576 B
  float* hin   = (float*)(ws + 72351744);       //  1,048,576 B

  cast_w_kernel<<<(D_DIM * D_DIM) / 256, 256, 0, stream>>>(gw, ow, gw16, ow16, D_DIM * D_DIM);
  ssm_pass1<<<B_DIM * NC * (D_DIM / 256), 256, 0, stream>>>(x, A, Bp, hfin);
  ssm_pass2<<<(B_DIM * D_DIM) / 256, 256, 0, stream>>>(A, hfin, hin);
  ssm_pass3<<<B_DIM * NC * (D_DIM / 256), 256, 0, stream>>>(x, A, Bp, Cp, hin, ssm16, x16);

  // gate GEMM: y = sigmoid(x@gw^T + gb) * ssm   (written in-place over ssm16)
  gemm128<true><<<GM * GN, 256, 0, stream>>>(x16, gw16, gb, ssm16, ssm16, nullptr);
  // out GEMM: out = y@ow^T + ob  (fp32)
  gemm128<false><<<GM * GN, 256, 0, stream>>>(ssm16, ow16, ob, nullptr, nullptr, out);
}

// Round 9
// 130.004 us; speedup vs baseline: 1.0538x; 1.0538x over previous
//
#include <hip/hip_runtime.h>
#include <hip/hip_bf16.h>
#include <cstdio>

typedef __hip_bfloat16 bf16;
typedef __bf16 bf16x8 __attribute__((ext_vector_type(8)));
typedef float f32x4 __attribute__((ext_vector_type(4)));

#define B_DIM 4
#define T_DIM 4096
#define D_DIM 1024
#define NC 64   // chunks along T
#define LC 64   // chunk length; NC*LC == T_DIM

#define M_DIM (B_DIM * T_DIM)  // 16384
#define BM 256
#define BN 256
#define BK 32
#define NT (D_DIM / BK)        // 32 K-tiles
#define GM (M_DIM / BM)        // 64
#define GN (D_DIM / BN)        // 4

// ---------------------------------------------------------------- weight cast
__global__ __launch_bounds__(256) void cast_w_kernel(
    const float* __restrict__ gw, const float* __restrict__ ow,
    bf16* __restrict__ gw16, bf16* __restrict__ ow16, int n) {
  int i = blockIdx.x * 256 + threadIdx.x;
  if (i < n) {
    gw16[i] = __float2bfloat16(gw[i]);
    ow16[i] = __float2bfloat16(ow[i]);
  }
}

// ---------------------------------------------------------------- SSM pass 1
__global__ __launch_bounds__(256) void ssm_pass1(
    const float* __restrict__ x, const float* __restrict__ A,
    const float* __restrict__ Bp, float* __restrict__ hfin) {
  const int tid  = threadIdx.x;
  const int dblk = blockIdx.x & 3;           // D/256 = 4
  const int c    = (blockIdx.x >> 2) & (NC - 1);
  const int b    = blockIdx.x >> 8;          // / (4*NC)
  const int d    = dblk * 256 + tid;
  const float a = A[d], bp = Bp[d];
  const float* p = x + ((size_t)(b * T_DIM + c * LC) * D_DIM + d);
  float h = 0.f;
#pragma unroll 4
  for (int i = 0; i < LC; ++i)
    h = fmaf(a, h, bp * p[(size_t)i * D_DIM]);
  hfin[(b * NC + c) * D_DIM + d] = h;
}

// ---------------------------------------------------------------- SSM pass 2
__global__ __launch_bounds__(256) void ssm_pass2(
    const float* __restrict__ A, const float* __restrict__ hfin,
    float* __restrict__ hin) {
  const int idx = blockIdx.x * 256 + threadIdx.x;  // B*D = 4096
  const int d = idx & (D_DIM - 1);
  const int b = idx >> 10;
  float aL = A[d];
#pragma unroll
  for (int s = 0; s < 6; ++s) aL *= aL;  // A^64 (LC = 2^6)
  float h = 0.f;
  for (int c = 0; c < NC; ++c) {
    const int o = (b * NC + c) * D_DIM + d;
    hin[o] = h;
    h = fmaf(aL, h, hfin[o]);
  }
}

// ---------------------------------------------------------------- SSM pass 3
__global__ __launch_bounds__(256) void ssm_pass3(
    const float* __restrict__ x, const float* __restrict__ A,
    const float* __restrict__ Bp, const float* __restrict__ Cp,
    const float* __restrict__ hin, bf16* __restrict__ ssm16,
    bf16* __restrict__ x16) {
  const int tid  = threadIdx.x;
  const int dblk = blockIdx.x & 3;
  const int c    = (blockIdx.x >> 2) & (NC - 1);
  const int b    = blockIdx.x >> 8;
  const int d    = dblk * 256 + tid;
  const float a = A[d], bp = Bp[d], cp = Cp[d];
  float h = hin[(b * NC + c) * D_DIM + d];
  const size_t base = (size_t)(b * T_DIM + c * LC) * D_DIM + d;
#pragma unroll 4
  for (int i = 0; i < LC; ++i) {
    const size_t o = base + (size_t)i * D_DIM;
    const float xv = x[o];
    h = fmaf(a, h, bp * xv);
    ssm16[o] = __float2bfloat16(cp * h);
    x16[o]  = __float2bfloat16(xv);
  }
}

// ---------------------------------------------------------------- GEMM 256x256
// C[m][e] = sum_k X[m][k] * W[e][k]  (+bias, +epilogue)
// R9 = R7 structure (best measured: 48.8us, 710 TF) with the schedule
// UNPINNED: the lgkmcnt(0)+sched_barrier(0) pair is removed. Rule #18
// applies only to inline-asm ds_reads; ours are plain loads, so the
// compiler emits fine-grained lgkmcnt(N) before each MFMA use and can
// overlap the 12-read latency with the first MFMAs (m97 behavior).
// Everything else identical to R7: 256x256 tile, BK=32, 8 waves (2Mx4N),
// ring-4 LDS, prefetch distance 3, counted vmcnt (T4), T2 XOR swizzle
// both-sides (conflicts measured 0), T5 setprio, mid-tile single barrier
// with split MFMA halves, XCD-chunked block swizzle.
template <bool GATE>
__global__ __launch_bounds__(512) void gemm256(
    const bf16* __restrict__ Xm, const bf16* __restrict__ Wm,
    const float* __restrict__ bias, const bf16* __restrict__ ssm,
    bf16* __restrict__ Ybf, float* __restrict__ Yf) {
  // buf layout (shorts): [0,8192) = A tile 256x32, [8192,16384) = B tile 256x32
  __shared__ __align__(16) short LDS[4][16384];  // 4 x 32 KiB = 128 KiB

  const int tid  = threadIdx.x;
  const int lane = tid & 63;
  const int wave = tid >> 6;
  const int wm = wave >> 2;           // 0..1
  const int wn = wave & 3;            // 0..3
  const int l15 = lane & 15;
  // swizzled ds_read slot: true chunk (lane>>4), row parity term (l15>>1)&3
  const int sA = ((lane >> 4) ^ ((l15 >> 1) & 3)) << 3;  // shorts

  // XCD-chunked swizzle (256 blocks, 8 XCDs): 4 N-blocks per M-row share L2.
  const int bid = blockIdx.x;
  const int swz = (bid & 7) * (GM * GN / 8) + (bid >> 3);
  const int m0 = (swz >> 2) * BM;
  const int n0 = (swz & 3) * BN;

  // staging: linear LDS chunk cid -> row=cid>>2, slot=cid&3; global col-chunk
  // c = slot ^ ((row>>1)&3)  (involution matches sA on the read side).
  const int row0 = tid >> 2;
  const int c0   = (tid & 3) ^ ((row0 >> 1) & 3);
  const size_t offA0 = (size_t)(m0 + row0) * D_DIM + c0 * 8;
  const size_t offB0 = (size_t)(n0 + row0) * D_DIM + c0 * 8;

  auto gll = [](const bf16* g, short* l) {
    __builtin_amdgcn_global_load_lds(
        (const __attribute__((address_space(1))) void*)g,
        (__attribute__((address_space(3))) void*)l, 16, 0, 0);
  };
  auto STAGE = [&](int buf, int kt) {
    const size_t ko = (size_t)kt * BK;
    short* b0 = &LDS[buf][0] + wave * 512;
    gll(Xm + offA0 + ko,               b0);
    gll(Xm + offA0 + 128 * D_DIM + ko, b0 + 4096);
    gll(Wm + offB0 + ko,               b0 + 8192);
    gll(Wm + offB0 + 128 * D_DIM + ko, b0 + 12288);
  };

  f32x4 acc[8][4] = {};

  // prologue: prime tiles 0,1,2 (12 loads/wave in flight)
  STAGE(0, 0);
  STAGE(1, 1);
  STAGE(2, 2);
  asm volatile("s_waitcnt vmcnt(8)" ::: "memory");
  __builtin_amdgcn_s_barrier();  // tile 0 staged for all waves

#define KTILE_BODY(T_, VMSTR, DO_STAGE, DO_BAR)                             \
  {                                                                         \
    const short* bb = &LDS[(T_) & 3][0];                                    \
    bf16x8 a[8], b[4];                                                      \
    /* half1 deps first: a[0..3], b[0..3]; then a[4..7] */                  \
    _Pragma("unroll")                                                       \
    for (int i = 0; i < 4; ++i)                                             \
      a[i] = *(const bf16x8*)(bb + (wm * 128 + i * 16 + l15) * BK + sA);    \
    _Pragma("unroll")                                                       \
    for (int j = 0; j < 4; ++j)                                             \
      b[j] = *(const bf16x8*)(bb + 8192 + (wn * 64 + j * 16 + l15) * BK + sA); \
    _Pragma("unroll")                                                       \
    for (int i = 4; i < 8; ++i)                                             \
      a[i] = *(const bf16x8*)(bb + (wm * 128 + i * 16 + l15) * BK + sA);    \
    if (DO_STAGE) STAGE(((T_) + 3) & 3, (T_) + 3);                          \
    /* no lgkmcnt(0)/sched_barrier pin: plain loads, compiler emits */      \
    /* fine-grained lgkmcnt(N) and overlaps reads with first MFMAs  */      \
    __builtin_amdgcn_s_setprio(1);                                          \
    _Pragma("unroll")                                                       \
    for (int i = 0; i < 4; ++i)                                             \
      _Pragma("unroll")                                                     \
      for (int j = 0; j < 4; ++j)                                           \
        acc[i][j] =                                                         \
            __builtin_amdgcn_mfma_f32_16x16x32_bf16(a[i], b[j], acc[i][j], 0, 0, 0); \
    __builtin_amdgcn_s_setprio(0);                                          \
    if (DO_BAR) {                                                           \
      asm volatile("s_waitcnt " VMSTR ::: "memory");                        \
      __builtin_amdgcn_s_barrier();                                         \
    }                                                                       \
    __builtin_amdgcn_s_setprio(1);                                          \
    _Pragma("unroll")                                                       \
    for (int i = 4; i < 8; ++i)                                             \
      _Pragma("unroll")                                                     \
      for (int j = 0; j < 4; ++j)                                           \
        acc[i][j] =                                                         \
            __builtin_amdgcn_mfma_f32_16x16x32_bf16(a[i], b[j], acc[i][j], 0, 0, 0); \
    __builtin_amdgcn_s_setprio(0);                                          \
  }

  for (int t = 0; t < NT - 3; ++t)        // t = 0..28: stage t+3 = 3..31
    KTILE_BODY(t, "vmcnt(8)", true, true);
  KTILE_BODY(NT - 3, "vmcnt(4)", false, true);  // ensure tile NT-2 landed
  KTILE_BODY(NT - 2, "vmcnt(0)", false, true);  // ensure tile NT-1 landed
  KTILE_BODY(NT - 1, "vmcnt(0)", false, false); // last tile: no barrier
#undef KTILE_BODY

  // ---- epilogue: C/D layout col = lane&15, row = (lane>>4)*4 + v  [m89/m91]
#pragma unroll
  for (int i = 0; i < 8; ++i) {
#pragma unroll
    for (int j = 0; j < 4; ++j) {
      const int col = n0 + wn * 64 + j * 16 + l15;
      const float bv = bias[col];
#pragma unroll
      for (int v = 0; v < 4; ++v) {
        const int row = m0 + wm * 128 + i * 16 + (lane >> 4) * 4 + v;
        const size_t o = (size_t)row * D_DIM + col;
        const float val = acc[i][j][v] + bv;
        if (GATE) {
          const float g = 1.f / (1.f + expf(-val));
          Ybf[o] = __float2bfloat16(g * __bfloat162float(ssm[o]));
        } else {
          Yf[o] = val;
        }
      }
    }
  }
}

// ---------------------------------------------------------------- launch
extern "C" void kernel_launch(void* const* d_in, const int* in_sizes, int n_in,
                              void* d_out, int out_size, void* d_ws, size_t ws_size,
                              hipStream_t stream) {
  const float* x  = (const float*)d_in[0];
  const float* A  = (const float*)d_in[1];
  const float* Bp = (const float*)d_in[2];
  const float* Cp = (const float*)d_in[3];
  const float* gw = (const float*)d_in[4];
  const float* gb = (const float*)d_in[5];
  const float* ow = (const float*)d_in[6];
  const float* ob = (const float*)d_in[7];
  float* out = (float*)d_out;

  // workspace layout (bytes)
  const size_t NEED = 73400320;
  if (ws_size < NEED) {
    fprintf(stderr, "kernel_launch: ws_size %zu < needed %zu\n", ws_size, NEED);
    return;
  }
  char* ws = (char*)d_ws;
  bf16*  x16   = (bf16*)(ws);                   // 33,554,432 B : x cast to bf16
  bf16*  ssm16 = (bf16*)(ws + 33554432);        // 33,554,432 B : ssm, then y in-place
  bf16*  gw16  = (bf16*)(ws + 67108864);        //  2,097,152 B
  bf16*  ow16  = (bf16*)(ws + 69206016);        //  2,097,152 B
  float* hfin  = (float*)(ws + 71303168);       //  1,048,576 B
  float* hin   = (float*)(ws + 72351744);       //  1,048,576 B

  cast_w_kernel<<<(D_DIM * D_DIM) / 256, 256, 0, stream>>>(gw, ow, gw16, ow16, D_DIM * D_DIM);
  ssm_pass1<<<B_DIM * NC * (D_DIM / 256), 256, 0, stream>>>(x, A, Bp, hfin);
  ssm_pass2<<<(B_DIM * D_DIM) / 256, 256, 0, stream>>>(A, hfin, hin);
  ssm_pass3<<<B_DIM * NC * (D_DIM / 256), 256, 0, stream>>>(x, A, Bp, Cp, hin, ssm16, x16);

  // gate GEMM: y = sigmoid(x@gw^T + gb) * ssm   (written in-place over ssm16)
  gemm256<true><<<GM * GN, 512, 0, stream>>>(x16, gw16, gb, ssm16, ssm16, nullptr);
  // out GEMM: out = y@ow^T + ob  (fp32)
  gemm256<false><<<GM * GN, 512, 0, stream>>>(ssm16, ow16, ob, nullptr, nullptr, out);
}